// Round 4
// baseline (74.192 us; speedup 1.0000x reference)
//
#include <hip/hip_runtime.h>

// SeparationLoss: mean over B of sum_{i!=j} max(0, thr^2 - ||kp_i - kp_j||^2)
// B = 131072, J = 17, 3 floats per joint -> 51 floats per batch.
//
// Two-pass, atomic-free:
//   pass 1: 2048 blocks x 64 threads (ONE wave per block -> __syncthreads is a
//           bare waitcnt, no s_barrier). Wave stages its contiguous
//           64*51*4 = 13056 B slice via float4, each thread computes one batch
//           from LDS (row stride 51 floats, odd -> 2 lanes/bank = free).
//           Block partial -> plain store d_ws[blockIdx].
//   pass 2: 1 block x 256 threads reduces 2048 partials (float4 coalesced),
//           scales by 2/B, plain store to d_out.
// No atomics (R2 showed 2048 same-address atomicAdds cost ~21 us serialized).

#define NJ      17
#define KPF     51          // floats per batch (17*3)
#define BPB     64          // batches per block (pass 1)
#define T1      64          // pass-1 threads (single wave)
#define T2      256         // pass-2 threads
#define NPART   2048        // pass-1 grid = B / BPB

__global__ __launch_bounds__(T1)
void sep_loss_partial(const float* __restrict__ kps,
                      float* __restrict__ partial,
                      float thr2) {
    __shared__ float lds[BPB * KPF];            // 13056 B -> ~12 blocks/CU LDS cap

    const int tid = threadIdx.x;
    const long long b0 = (long long)blockIdx.x * BPB;

    // ---- Stage 64 batches (contiguous, 16B-aligned: b0*51*4 % 16 == 0) ----
    const float4* __restrict__ src4 =
        reinterpret_cast<const float4*>(kps + b0 * KPF);
    float4* dst4 = reinterpret_cast<float4*>(lds);
    const int n4 = BPB * KPF / 4;               // 816 float4s
    for (int i = tid; i < n4; i += T1) dst4[i] = src4[i];
    __syncthreads();                             // 1-wave block: waitcnt only

    // ---- One batch per thread ----
    float kp[KPF];
    const float* my = lds + tid * KPF;
    #pragma unroll
    for (int k = 0; k < KPF; ++k) kp[k] = my[k];

    // m_i = thr2/2 - ||kp_i||^2 ; pair value = max(0, m_i + m_j + 2*dot)
    float m[NJ];
    #pragma unroll
    for (int i = 0; i < NJ; ++i) {
        float x = kp[i * 3], y = kp[i * 3 + 1], z = kp[i * 3 + 2];
        m[i] = 0.5f * thr2 - fmaf(x, x, fmaf(y, y, z * z));
    }

    float acc = 0.0f;
    #pragma unroll
    for (int i = 0; i < NJ; ++i) {
        #pragma unroll
        for (int j = i + 1; j < NJ; ++j) {
            float dot = fmaf(kp[i * 3],     kp[j * 3],
                       fmaf(kp[i * 3 + 1], kp[j * 3 + 1],
                            kp[i * 3 + 2] * kp[j * 3 + 2]));
            acc += fmaxf(fmaf(2.0f, dot, m[i] + m[j]), 0.0f);
        }
    }

    // ---- Wave-64 reduction -> one plain store ----
    #pragma unroll
    for (int off = 32; off > 0; off >>= 1)
        acc += __shfl_down(acc, off, 64);
    if (tid == 0) partial[blockIdx.x] = acc;
}

__global__ __launch_bounds__(T2)
void sep_loss_final(const float* __restrict__ partial,
                    float* __restrict__ out,
                    float scale /* 2/B */) {
    __shared__ float wsum[T2 / 64];
    const int tid = threadIdx.x;

    // 2048 partials = 512 float4s; each thread takes 2 (coalesced).
    const float4* __restrict__ p4 = reinterpret_cast<const float4*>(partial);
    float4 a = p4[tid];
    float4 b = p4[tid + T2];
    float acc = (a.x + a.y) + (a.z + a.w) + (b.x + b.y) + (b.z + b.w);

    #pragma unroll
    for (int off = 32; off > 0; off >>= 1)
        acc += __shfl_down(acc, off, 64);
    if ((tid & 63) == 0) wsum[tid >> 6] = acc;
    __syncthreads();
    if (tid == 0)
        out[0] = (wsum[0] + wsum[1] + wsum[2] + wsum[3]) * scale;
}

extern "C" void kernel_launch(void* const* d_in, const int* in_sizes, int n_in,
                              void* d_out, int out_size, void* d_ws, size_t ws_size,
                              hipStream_t stream) {
    const float* kps = (const float*)d_in[0];
    float* out = (float*)d_out;
    float* partial = (float*)d_ws;              // 2048 floats of scratch

    const int B = in_sizes[0] / KPF;            // 131072
    const float thr2 = 0.1f * 0.1f;             // THRESHOLD^2
    const float scale = 2.0f / (float)B;

    sep_loss_partial<<<B / BPB, T1, 0, stream>>>(kps, partial, thr2);
    sep_loss_final<<<1, T2, 0, stream>>>(partial, out, scale);
}